// Round 11
// baseline (340.721 us; speedup 1.0000x reference)
//
#include <hip/hip_runtime.h>
#include <math.h>

#define LN_EPS 1e-5f
#define LOG2E 1.44269504088896f
#define LN2   0.69314718055994531f

typedef float f4 __attribute__((ext_vector_type(4)));
typedef float f2 __attribute__((ext_vector_type(2)));
typedef int   i4 __attribute__((ext_vector_type(4)));
typedef short bf16x8 __attribute__((ext_vector_type(8)));

// d_ws layout (bytes):
//   [0, 98304)        frags: [layer8][slot6][half2][lane64][j8] bf16
//                     slots: 0=W2hi 1=W2lo 2=tG 3=tB 4=sG 5=sB
//   [98304, 139264)   params: [layer8][path2][vec5][r16][4] f32
//   [139264, 140032)  uniforms: [layer8][path2][12] f32
#define WS_PARM_OFF 98304
#define WS_UNIF_OFF 139264
#define WS_NEED 140032

// per-wave LDS region: T(2560) | Z(768) | ST(768) | FB(768) = 4864 B
#define WV_STRIDE 4864
#define Z_OFF  2560
#define ST_OFF 3328
#define FB_OFF 4096
// Z/ST/FB row stride: 6 floats (24B) — 6 coprime-ish with 32 banks: worst
// aliasing is r vs r+16 (2-way, free). f4 would be 16B-misaligned at odd
// rows, so wide accesses are split into f2 (8B-aligned at 24r+{0,8}).
#define RSTRIDE 6

#define WAITLGKM() do { \
    asm volatile("s_waitcnt lgkmcnt(0)" ::: "memory"); \
    __builtin_amdgcn_sched_barrier(0); \
} while (0)

__device__ __forceinline__ unsigned short rne_bf16(float f) {
    unsigned u = __builtin_bit_cast(unsigned, f);
    unsigned r = (u + 0x7FFFu + ((u >> 16) & 1u)) >> 16;
    return (unsigned short)r;
}

// packed f32->bf16 convert (RNE), one VALU op for two conversions
__device__ __forceinline__ unsigned cvt_pk_bf16(float lo, float hi) {
    unsigned r;
    asm("v_cvt_pk_bf16_f32 %0, %1, %2" : "=v"(r) : "v"(lo), "v"(hi));
    return r;
}

template <int CTRL>
__device__ __forceinline__ float dpp_add_step(float v) {
    int t = __builtin_amdgcn_update_dpp(0, __builtin_bit_cast(int, v), CTRL, 0xf, 0xf, true);
    return v + __builtin_bit_cast(float, t);
}
// sum across the 16-lane DPP row; result identical in all 16 lanes
__device__ __forceinline__ float reduce16(float v) {
    v = dpp_add_step<0xB1>(v);   // quad_perm(1,0,3,2)
    v = dpp_add_step<0x4E>(v);   // quad_perm(2,3,0,1)
    v = dpp_add_step<0x141>(v);  // row_half_mirror
    v = dpp_add_step<0x140>(v);  // row_mirror
    return v;
}

// ---------------- preprocessing (identical to round 10) ----------------
__global__ void preproc_kernel(
    const float* __restrict__ embW2, const float* __restrict__ embb2,
    const float* __restrict__ tW, const float* __restrict__ tb,
    const float* __restrict__ t_ln_g, const float* __restrict__ t_ln_b,
    const float* __restrict__ t_gW, const float* __restrict__ t_gb,
    const float* __restrict__ t_bW, const float* __restrict__ t_bb,
    const float* __restrict__ toW, const float* __restrict__ tob,
    const float* __restrict__ sW, const float* __restrict__ sb,
    const float* __restrict__ s_ln_g, const float* __restrict__ s_ln_b,
    const float* __restrict__ s_gW, const float* __restrict__ s_gb,
    const float* __restrict__ s_bW, const float* __restrict__ s_bb,
    const float* __restrict__ soW, const float* __restrict__ sob,
    unsigned short* __restrict__ ws16, float* __restrict__ wsP,
    float* __restrict__ wsU)
{
    const int i = blockIdx.x;
    const int tid = threadIdx.x;
    const int parity = i & 1;
    const int ka = parity ? 2 : 0, pa = parity ? 0 : 2;

    const float* fsrc[6] = {embW2 + i * 1024, embW2 + i * 1024,
                            t_gW + i * 1024, t_bW + i * 1024,
                            s_gW + i * 1024, s_bW + i * 1024};
    for (int e = tid; e < 6144; e += 256) {
        int s = e >> 10, e10 = e & 1023;
        int half = e10 >> 9, ln = (e10 >> 3) & 63, j = e10 & 7;
        int p8 = (ln >> 4) * 8 + j;
        int k = (s >= 2) ? ((p8 >> 1) | ((p8 & 1) << 4)) : p8;
        int c = half * 16 + (ln & 15);
        float w = fsrc[s][k * 32 + c];
        unsigned short hv = rne_bf16(w);
        if (s == 1) {
            float whi = __builtin_bit_cast(float, (unsigned)hv << 16);
            hv = rne_bf16(w - whi);
        }
        ws16[i * 6144 + s * 1024 + e10] = hv;
    }

    if (tid < 32) {
        int p = tid >> 4, r = tid & 15;
        const float* W   = (p ? sW : tW) + i * 128;
        const float* b   = (p ? sb : tb) + i * 32;
        const float* lng = (p ? s_ln_g : t_ln_g) + i * 32;
        const float* lnb = (p ? s_ln_b : t_ln_b) + i * 32;
        const float* gb  = (p ? s_gb : t_gb) + i * 32;
        const float* bb  = (p ? s_bb : t_bb) + i * 32;
        const float* ow  = (p ? soW : toW) + i * 128;
        float sc = p ? (2.0f * LOG2E) : 1.0f;
        int cL = r, cH = r + 16;
        float* dst = wsP + i * 640 + p * 320;
        f4 v0 = {W[ka*32+cL]*lng[cL], W[(ka+1)*32+cL]*lng[cL], b[cL]*lng[cL], lng[cL]};
        f4 v1 = {W[ka*32+cH]*lng[cH], W[(ka+1)*32+cH]*lng[cH], b[cH]*lng[cH], lng[cH]};
        f4 v2 = {lnb[cL], lnb[cH], gb[cL], gb[cH]};
        f4 v3 = {bb[cL], bb[cH], ow[cL*4+pa]*sc, ow[cL*4+pa+1]*sc};
        f4 v4 = {ow[cH*4+pa]*sc, ow[cH*4+pa+1]*sc, embb2[i*32+cL], embb2[i*32+cH]};
        *(f4*)(dst + 0*64 + r*4) = v0;
        *(f4*)(dst + 1*64 + r*4) = v1;
        *(f4*)(dst + 2*64 + r*4) = v2;
        *(f4*)(dst + 3*64 + r*4) = v3;
        *(f4*)(dst + 4*64 + r*4) = v4;
    } else if (tid < 34) {
        int p = tid - 32;
        const float* W  = (p ? sW : tW) + i * 128;
        const float* b  = (p ? sb : tb) + i * 32;
        const float* ob = (p ? sob : tob) + i * 4;
        float sc = p ? (2.0f * LOG2E) : 1.0f;
        float S0=0,S1=0,Sb=0,Q00=0,Q11=0,Qbb=0,Q01=0,Q0b=0,Q1b=0;
        for (int c = 0; c < 32; ++c) {
            float w0 = W[ka*32+c], w1 = W[(ka+1)*32+c], bc = b[c];
            S0+=w0; S1+=w1; Sb+=bc;
            Q00+=w0*w0; Q11+=w1*w1; Qbb+=bc*bc;
            Q01+=w0*w1; Q0b+=w0*bc; Q1b+=w1*bc;
        }
        const float inv32 = 1.0f / 32.0f;
        float* u = wsU + (i*2+p)*12;
        u[0]=S0*inv32; u[1]=S1*inv32; u[2]=Sb*inv32;
        u[3]=Q00*inv32; u[4]=2.0f*Q01*inv32; u[5]=2.0f*Q0b*inv32;
        u[6]=Q11*inv32; u[7]=2.0f*Q1b*inv32; u[8]=Qbb*inv32;
        u[9]=ob[pa]*sc*(1.0f/16.0f); u[10]=ob[pa+1]*sc*(1.0f/16.0f);
        u[11]=0.0f;
    }
}

// ---------------- one FiLM path; z and LN stats read from LDS ----------------
__device__ __forceinline__ void film_path(
    const unsigned short* __restrict__ fb, int slotg, int slotb, int lane,
    int kaf, int path, const float* Z, const float* ST,
    const bf16x8 a2[2], const f4 pv[5], const float* __restrict__ u,
    float (&f0)[2][4], float (&f1)[2][4])
{
    const int g = lane >> 4;
    bf16x8 gh0 = *(const bf16x8*)(fb + slotg * 1024 + lane * 8);
    bf16x8 gh1 = *(const bf16x8*)(fb + slotg * 1024 + 512 + lane * 8);
    bf16x8 bh0 = *(const bf16x8*)(fb + slotb * 1024 + lane * 8);
    bf16x8 bh1 = *(const bf16x8*)(fb + slotb * 1024 + 512 + lane * 8);
    float gbL = pv[2][2], gbH = pv[2][3], bbL = pv[3][0], bbH = pv[3][1];
    f4 cg0 = {gbL, gbL, gbL, gbL}, cg1 = {gbH, gbH, gbH, gbH};
    f4 cb0 = {bbL, bbL, bbL, bbL}, cb1 = {bbH, bbH, bbH, bbH};
    f4 gacc[2][2], bacc[2][2];
    #pragma unroll
    for (int t = 0; t < 2; ++t) {
        gacc[t][0] = __builtin_amdgcn_mfma_f32_16x16x32_bf16(a2[t], gh0, cg0, 0, 0, 0);
        gacc[t][1] = __builtin_amdgcn_mfma_f32_16x16x32_bf16(a2[t], gh1, cg1, 0, 0, 0);
        bacc[t][0] = __builtin_amdgcn_mfma_f32_16x16x32_bf16(a2[t], bh0, cb0, 0, 0, 0);
        bacc[t][1] = __builtin_amdgcn_mfma_f32_16x16x32_bf16(a2[t], bh1, cb1, 0, 0, 0);
    }
    float ob0 = u[9], ob1 = u[10];
    float wk0L=pv[0][0], wk1L=pv[0][1], bL=pv[0][2], lngL=pv[0][3];
    float wk0H=pv[1][0], wk1H=pv[1][1], bH=pv[1][2], lngH=pv[1][3];
    float lnbL=pv[2][0], lnbH=pv[2][1];
    float owL0=pv[3][2], owL1=pv[3][3], owH0=pv[4][0], owH1=pv[4][1];
    #pragma unroll
    for (int t = 0; t < 2; ++t) {
        #pragma unroll
        for (int q = 0; q < 4; ++q) {
            int rowl = 16 * t + 4 * g + q;
            f2 zkv = *(const f2*)(Z + rowl * RSTRIDE + kaf);       // broadcast read
            f2 st  = *(const f2*)(ST + rowl * RSTRIDE + path * 2); // {-m*rstd, rstd}
            float hL = fmaf(zkv[0], wk0L, fmaf(zkv[1], wk1L, bL));
            float hH = fmaf(zkv[0], wk0H, fmaf(zkv[1], wk1H, bH));
            float nL = fmaf(hL, st[1], fmaf(st[0], lngL, lnbL));
            float nH = fmaf(hH, st[1], fmaf(st[0], lngH, lnbH));
            float gL = gacc[t][0][q], gH = gacc[t][1][q];
            float btL = bacc[t][0][q], btH = bacc[t][1][q];
            float thL = fmaxf(fmaf(gL, nL, nL + btL), 0.0f);
            float thH = fmaxf(fmaf(gH, nH, nH + btH), 0.0f);
            float p0 = fmaf(thL, owL0, fmaf(thH, owH0, ob0));
            float p1 = fmaf(thL, owL1, fmaf(thH, owH1, ob1));
            f0[t][q] = reduce16(p0);
            f1[t][q] = reduce16(p1);
        }
    }
}

__global__ __launch_bounds__(256, 6) void realnvp_mfma(
    const float* __restrict__ x, const float* __restrict__ y,
    const float* __restrict__ embW1, const float* __restrict__ embb1,
    const unsigned short* __restrict__ ws16,
    const float* __restrict__ wsP, const float* __restrict__ wsU,
    float* __restrict__ out_z, float* __restrict__ out_ld)
{
    __shared__ __align__(16) unsigned char ldsbuf[4 * WV_STRIDE];
    const int lane = threadIdx.x & 63;
    const int wv = threadIdx.x >> 6;
    const int r = lane & 15, g = lane >> 4;
    const int rs = lane & 31, hw = lane >> 5;
    unsigned char* T = ldsbuf + wv * WV_STRIDE;            // 32 rows x 80B (e2 transpose)
    float* Z  = (float*)(ldsbuf + wv * WV_STRIDE + Z_OFF); // 32 rows x 6 floats (z)
    float* ST = (float*)(ldsbuf + wv * WV_STRIDE + ST_OFF);// 32 x {-mrT,rstdT,-mrS,rstdS,pad,pad}
    float* FB = (float*)(ldsbuf + wv * WV_STRIDE + FB_OFF);// 32 x {tf0,sf0,tf1,sf1,pad,pad}
    const int row0 = (blockIdx.x * 4 + wv) * 32;

    if (lane < 32) {
        f4 xv = *(const f4*)(x + (size_t)(row0 + rs) * 4);
        f2 lo = {xv.x, xv.y}, hi = {xv.z, xv.w};
        *(f2*)(Z + rs * RSTRIDE) = lo;
        *(f2*)(Z + rs * RSTRIDE + 2) = hi;
    }
    f4 y4[2];
    y4[0] = *(const f4*)(y + (size_t)(row0 + r) * 4);
    y4[1] = *(const f4*)(y + (size_t)(row0 + 16 + r) * 4);
    float ld2 = 0.0f;
    WAITLGKM();

    #pragma unroll 1
    for (int i = 0; i < 8; ++i) {
        const int parity = i & 1;
        const int kaf = parity ? 2 : 0;   // kept-dim offset in z row
        const int pa  = parity ? 0 : 2;   // transform-dim base
        const unsigned short* fb = ws16 + i * 6144;
        const float* pP = wsP + i * 640;
        const float* uT = wsU + (i * 2) * 12;
        const float* uS = uT + 12;

        // ---- LN stats: row-per-lane, paths split across half-waves ----
        {
            f2 zk = *(const f2*)(Z + rs * RSTRIDE + kaf);
            const float* ub = wsU + (i * 2 + hw) * 12;
            f4 u0 = *(const f4*)(ub);        // {S0,S1,Sb,Q00}
            f4 u1 = *(const f4*)(ub + 4);    // {Q01,Q0b,Q11,Q1b}
            f4 u2 = *(const f4*)(ub + 8);    // {Qbb,obc0,obc1,0}
            float za = zk[0], zb = zk[1];
            float m   = fmaf(za, u0[0], fmaf(zb, u0[1], u0[2]));
            float ex2 = fmaf(za, fmaf(za, u0[3], fmaf(zb, u1[0], u1[1])),
                             fmaf(zb, fmaf(zb, u1[2], u1[3]), u2[0]));
            float var = fmaxf(fmaf(-m, m, ex2), 0.0f);
            float rstd = __builtin_amdgcn_rsqf(var + LN_EPS);
            f2 stv = {-m * rstd, rstd};
            *(f2*)(ST + rs * RSTRIDE + hw * 2) = stv;
        }

        f4 ptv[5];
        #pragma unroll
        for (int v = 0; v < 5; ++v) ptv[v] = *(const f4*)(pP + v * 64 + r * 4);

        // ---- e1 = relu(y @ W1 + b1) directly in A-fragment layout ----
        const float* W1 = embW1 + i * 128;
        f4 w1a[4], w1b[4];
        #pragma unroll
        for (int c = 0; c < 4; ++c) {
            w1a[c] = *(const f4*)(W1 + c * 32 + g * 8);
            w1b[c] = *(const f4*)(W1 + c * 32 + g * 8 + 4);
        }
        f4 b1a = *(const f4*)(embb1 + i * 32 + g * 8);
        f4 b1b = *(const f4*)(embb1 + i * 32 + g * 8 + 4);
        bf16x8 a1[2];
        #pragma unroll
        for (int t = 0; t < 2; ++t) {
            unsigned aw[4];
            #pragma unroll
            for (int jp = 0; jp < 4; ++jp) {
                const int j0 = 2 * jp, j1 = 2 * jp + 1;
                float aL = (j0 < 4) ? b1a[j0 & 3] : b1b[j0 & 3];
                float aH = (j1 < 4) ? b1a[j1 & 3] : b1b[j1 & 3];
                #pragma unroll
                for (int c = 0; c < 4; ++c) {
                    aL = fmaf(y4[t][c], (j0 < 4) ? w1a[c][j0 & 3] : w1b[c][j0 & 3], aL);
                    aH = fmaf(y4[t][c], (j1 < 4) ? w1a[c][j1 & 3] : w1b[c][j1 & 3], aH);
                }
                aw[jp] = cvt_pk_bf16(fmaxf(aL, 0.0f), fmaxf(aH, 0.0f));
            }
            i4 ai = {(int)aw[0], (int)aw[1], (int)aw[2], (int)aw[3]};
            a1[t] = __builtin_bit_cast(bf16x8, ai);
        }

        // ---- e2 = relu(e1 @ W2 + b2) via MFMA (hi+lo weights, bias in C) ----
        bf16x8 w2h0 = *(const bf16x8*)(fb + lane * 8);
        bf16x8 w2h1 = *(const bf16x8*)(fb + 512 + lane * 8);
        bf16x8 w2l0 = *(const bf16x8*)(fb + 1024 + lane * 8);
        bf16x8 w2l1 = *(const bf16x8*)(fb + 1536 + lane * 8);
        float b2L = ptv[4][2], b2H = ptv[4][3];
        f4 c2L = {b2L, b2L, b2L, b2L}, c2H = {b2H, b2H, b2H, b2H};
        f4 e2a[2][2];
        #pragma unroll
        for (int t = 0; t < 2; ++t) {
            e2a[t][0] = __builtin_amdgcn_mfma_f32_16x16x32_bf16(a1[t], w2h0, c2L, 0, 0, 0);
            e2a[t][0] = __builtin_amdgcn_mfma_f32_16x16x32_bf16(a1[t], w2l0, e2a[t][0], 0, 0, 0);
            e2a[t][1] = __builtin_amdgcn_mfma_f32_16x16x32_bf16(a1[t], w2h1, c2H, 0, 0, 0);
            e2a[t][1] = __builtin_amdgcn_mfma_f32_16x16x32_bf16(a1[t], w2l1, e2a[t][1], 0, 0, 0);
        }

        // ---- D-layout -> A-layout transpose through LDS ----
        #pragma unroll
        for (int t = 0; t < 2; ++t)
            #pragma unroll
            for (int q = 0; q < 4; ++q) {
                int rowl = 16 * t + 4 * g + q;
                float vl = fmaxf(e2a[t][0][q], 0.0f);
                float vh = fmaxf(e2a[t][1][q], 0.0f);
                *(unsigned*)(T + rowl * 80 + r * 4) = cvt_pk_bf16(vl, vh);
            }
        WAITLGKM();   // drains T pack AND the ST stat write above
        bf16x8 a2[2];
        a2[0] = *(const bf16x8*)(T + r * 80 + g * 16);
        a2[1] = *(const bf16x8*)(T + (16 + r) * 80 + g * 16);

        // ---- t and s FiLM paths (z, stats from LDS) ----
        float tf0[2][4], tf1[2][4], sf0[2][4], sf1[2][4];
        film_path(fb, 2, 3, lane, kaf, 0, Z, ST, a2, ptv, uT, tf0, tf1);
        f4 psv[5];
        #pragma unroll
        for (int v = 0; v < 5; ++v) psv[v] = *(const f4*)(pP + 320 + v * 64 + r * 4);
        film_path(fb, 4, 5, lane, kaf, 1, Z, ST, a2, psv, uS, sf0, sf1);

        // ---- publish per-row results (one writer lane per group) ----
        if (r == 0) {
            #pragma unroll
            for (int t = 0; t < 2; ++t)
                #pragma unroll
                for (int q = 0; q < 4; ++q) {
                    int rowl = 16 * t + 4 * g + q;
                    f2 lo = {tf0[t][q], sf0[t][q]};
                    f2 hi = {tf1[t][q], sf1[t][q]};
                    *(f2*)(FB + rowl * RSTRIDE) = lo;
                    *(f2*)(FB + rowl * RSTRIDE + 2) = hi;
                }
        }
        WAITLGKM();

        // ---- coupling tail: row-per-lane, dims split across half-waves ----
        {
            int d = pa + hw;
            f2 fv = *(const f2*)(FB + rs * RSTRIDE + hw * 2);   // {tf_d, sf_d}
            float e  = __builtin_amdgcn_exp2f(fv[1]);     // sf pre-scaled by 2*log2e
            float rc = __builtin_amdgcn_rcpf(e + 1.0f);
            float s2 = fmaf(-2.0f * LOG2E, rc, LOG2E);    // tanh(.)*log2e
            float eA = __builtin_amdgcn_exp2f(s2);
            float zo = Z[rs * RSTRIDE + d];
            Z[rs * RSTRIDE + d] = fmaf(zo, eA, fv[0]);
            ld2 += s2;
        }
        WAITLGKM();
    }

    float oth = __shfl(ld2, lane ^ 32, 64);
    float ldv = (ld2 + oth) * LN2;
    if (lane < 32) {
        f2 lo = *(const f2*)(Z + rs * RSTRIDE);
        f2 hi = *(const f2*)(Z + rs * RSTRIDE + 2);
        f4 zo = {lo[0], lo[1], hi[0], hi[1]};
        *(f4*)(out_z + (size_t)(row0 + rs) * 4) = zo;
        out_ld[row0 + rs] = ldv;
    }
}

extern "C" void kernel_launch(void* const* d_in, const int* in_sizes, int n_in,
                              void* d_out, int out_size, void* d_ws, size_t ws_size,
                              hipStream_t stream) {
    const float* x      = (const float*)d_in[0];
    const float* y      = (const float*)d_in[1];
    const float* embW1  = (const float*)d_in[2];
    const float* embb1  = (const float*)d_in[3];
    const float* embW2  = (const float*)d_in[4];
    const float* embb2  = (const float*)d_in[5];
    const float* tW     = (const float*)d_in[6];
    const float* tb     = (const float*)d_in[7];
    const float* t_ln_g = (const float*)d_in[8];
    const float* t_ln_b = (const float*)d_in[9];
    const float* t_gW   = (const float*)d_in[10];
    const float* t_gb   = (const float*)d_in[11];
    const float* t_bW   = (const float*)d_in[12];
    const float* t_bb   = (const float*)d_in[13];
    const float* toW    = (const float*)d_in[14];
    const float* tob    = (const float*)d_in[15];
    const float* sW     = (const float*)d_in[16];
    const float* sb     = (const float*)d_in[17];
    const float* s_ln_g = (const float*)d_in[18];
    const float* s_ln_b = (const float*)d_in[19];
    const float* s_gW   = (const float*)d_in[20];
    const float* s_gb   = (const float*)d_in[21];
    const float* s_bW   = (const float*)d_in[22];
    const float* s_bb   = (const float*)d_in[23];
    const float* soW    = (const float*)d_in[24];
    const float* sob    = (const float*)d_in[25];

    if (ws_size < WS_NEED) return;
    unsigned short* ws16 = (unsigned short*)d_ws;
    float* wsP = (float*)((char*)d_ws + WS_PARM_OFF);
    float* wsU = (float*)((char*)d_ws + WS_UNIF_OFF);

    int B = in_sizes[0] / 4;
    float* out_z  = (float*)d_out;
    float* out_ld = out_z + (size_t)B * 4;

    hipLaunchKernelGGL(preproc_kernel, dim3(8), dim3(256), 0, stream,
                       embW2, embb2, tW, tb, t_ln_g, t_ln_b, t_gW, t_gb,
                       t_bW, t_bb, toW, tob, sW, sb, s_ln_g, s_ln_b,
                       s_gW, s_gb, s_bW, s_bb, soW, sob, ws16, wsP, wsU);
    hipLaunchKernelGGL(realnvp_mfma, dim3(B / 128), dim3(256), 0, stream,
                       x, y, embW1, embb1, ws16, wsP, wsU, out_z, out_ld);
}

// Round 12
// 121.552 us; speedup vs baseline: 2.8031x; 2.8031x over previous
//
#include <hip/hip_runtime.h>
#include <math.h>

#define LN_EPS 1e-5f
#define LOG2E 1.44269504088896f
#define LN2   0.69314718055994531f

typedef float f4 __attribute__((ext_vector_type(4)));
typedef float f2 __attribute__((ext_vector_type(2)));
typedef int   i4 __attribute__((ext_vector_type(4)));
typedef short bf16x8 __attribute__((ext_vector_type(8)));

// d_ws layout (bytes):
//   [0, 98304)        frags: [layer8][slot6][half2][lane64][j8] bf16
//                     slots: 0=W2hi 1=W2lo 2=tG 3=tB 4=sG 5=sB
//   [98304, 139264)   params: [layer8][path2][vec5][r16][4] f32
//   [139264, 140032)  uniforms: [layer8][path2][12] f32
#define WS_PARM_OFF 98304
#define WS_UNIF_OFF 139264
#define WS_NEED 140032

// per-wave LDS region: T(2560) | Z(768) | ST(768) | FB(768) = 4864 B
#define WV_STRIDE 4864
#define Z_OFF  2560
#define ST_OFF 3328
#define FB_OFF 4096
// Z/ST/FB row stride: 6 floats (24B) — worst aliasing r vs r+16 = 2-way (free).
// f4 would be 16B-misaligned at odd rows, so wide accesses split into f2.
#define RSTRIDE 6

#define WAITLGKM() do { \
    asm volatile("s_waitcnt lgkmcnt(0)" ::: "memory"); \
    __builtin_amdgcn_sched_barrier(0); \
} while (0)

__device__ __forceinline__ unsigned short rne_bf16(float f) {
    unsigned u = __builtin_bit_cast(unsigned, f);
    unsigned r = (u + 0x7FFFu + ((u >> 16) & 1u)) >> 16;
    return (unsigned short)r;
}

// packed f32->bf16 convert (RNE), one VALU op for two conversions
__device__ __forceinline__ unsigned cvt_pk_bf16(float lo, float hi) {
    unsigned r;
    asm("v_cvt_pk_bf16_f32 %0, %1, %2" : "=v"(r) : "v"(lo), "v"(hi));
    return r;
}

template <int CTRL>
__device__ __forceinline__ float dpp_add_step(float v) {
    int t = __builtin_amdgcn_update_dpp(0, __builtin_bit_cast(int, v), CTRL, 0xf, 0xf, true);
    return v + __builtin_bit_cast(float, t);
}
// sum across the 16-lane DPP row; result identical in all 16 lanes
__device__ __forceinline__ float reduce16(float v) {
    v = dpp_add_step<0xB1>(v);   // quad_perm(1,0,3,2)
    v = dpp_add_step<0x4E>(v);   // quad_perm(2,3,0,1)
    v = dpp_add_step<0x141>(v);  // row_half_mirror
    v = dpp_add_step<0x140>(v);  // row_mirror
    return v;
}

// ---------------- preprocessing (identical to round 10/11) ----------------
__global__ void preproc_kernel(
    const float* __restrict__ embW2, const float* __restrict__ embb2,
    const float* __restrict__ tW, const float* __restrict__ tb,
    const float* __restrict__ t_ln_g, const float* __restrict__ t_ln_b,
    const float* __restrict__ t_gW, const float* __restrict__ t_gb,
    const float* __restrict__ t_bW, const float* __restrict__ t_bb,
    const float* __restrict__ toW, const float* __restrict__ tob,
    const float* __restrict__ sW, const float* __restrict__ sb,
    const float* __restrict__ s_ln_g, const float* __restrict__ s_ln_b,
    const float* __restrict__ s_gW, const float* __restrict__ s_gb,
    const float* __restrict__ s_bW, const float* __restrict__ s_bb,
    const float* __restrict__ soW, const float* __restrict__ sob,
    unsigned short* __restrict__ ws16, float* __restrict__ wsP,
    float* __restrict__ wsU)
{
    const int i = blockIdx.x;
    const int tid = threadIdx.x;
    const int parity = i & 1;
    const int ka = parity ? 2 : 0, pa = parity ? 0 : 2;

    const float* fsrc[6] = {embW2 + i * 1024, embW2 + i * 1024,
                            t_gW + i * 1024, t_bW + i * 1024,
                            s_gW + i * 1024, s_bW + i * 1024};
    for (int e = tid; e < 6144; e += 256) {
        int s = e >> 10, e10 = e & 1023;
        int half = e10 >> 9, ln = (e10 >> 3) & 63, j = e10 & 7;
        int p8 = (ln >> 4) * 8 + j;
        int k = (s >= 2) ? ((p8 >> 1) | ((p8 & 1) << 4)) : p8;
        int c = half * 16 + (ln & 15);
        float w = fsrc[s][k * 32 + c];
        unsigned short hv = rne_bf16(w);
        if (s == 1) {
            float whi = __builtin_bit_cast(float, (unsigned)hv << 16);
            hv = rne_bf16(w - whi);
        }
        ws16[i * 6144 + s * 1024 + e10] = hv;
    }

    if (tid < 32) {
        int p = tid >> 4, r = tid & 15;
        const float* W   = (p ? sW : tW) + i * 128;
        const float* b   = (p ? sb : tb) + i * 32;
        const float* lng = (p ? s_ln_g : t_ln_g) + i * 32;
        const float* lnb = (p ? s_ln_b : t_ln_b) + i * 32;
        const float* gb  = (p ? s_gb : t_gb) + i * 32;
        const float* bb  = (p ? s_bb : t_bb) + i * 32;
        const float* ow  = (p ? soW : toW) + i * 128;
        float sc = p ? (2.0f * LOG2E) : 1.0f;
        int cL = r, cH = r + 16;
        float* dst = wsP + i * 640 + p * 320;
        f4 v0 = {W[ka*32+cL]*lng[cL], W[(ka+1)*32+cL]*lng[cL], b[cL]*lng[cL], lng[cL]};
        f4 v1 = {W[ka*32+cH]*lng[cH], W[(ka+1)*32+cH]*lng[cH], b[cH]*lng[cH], lng[cH]};
        f4 v2 = {lnb[cL], lnb[cH], gb[cL], gb[cH]};
        f4 v3 = {bb[cL], bb[cH], ow[cL*4+pa]*sc, ow[cL*4+pa+1]*sc};
        f4 v4 = {ow[cH*4+pa]*sc, ow[cH*4+pa+1]*sc, embb2[i*32+cL], embb2[i*32+cH]};
        *(f4*)(dst + 0*64 + r*4) = v0;
        *(f4*)(dst + 1*64 + r*4) = v1;
        *(f4*)(dst + 2*64 + r*4) = v2;
        *(f4*)(dst + 3*64 + r*4) = v3;
        *(f4*)(dst + 4*64 + r*4) = v4;
    } else if (tid < 34) {
        int p = tid - 32;
        const float* W  = (p ? sW : tW) + i * 128;
        const float* b  = (p ? sb : tb) + i * 32;
        const float* ob = (p ? sob : tob) + i * 4;
        float sc = p ? (2.0f * LOG2E) : 1.0f;
        float S0=0,S1=0,Sb=0,Q00=0,Q11=0,Qbb=0,Q01=0,Q0b=0,Q1b=0;
        for (int c = 0; c < 32; ++c) {
            float w0 = W[ka*32+c], w1 = W[(ka+1)*32+c], bc = b[c];
            S0+=w0; S1+=w1; Sb+=bc;
            Q00+=w0*w0; Q11+=w1*w1; Qbb+=bc*bc;
            Q01+=w0*w1; Q0b+=w0*bc; Q1b+=w1*bc;
        }
        const float inv32 = 1.0f / 32.0f;
        float* u = wsU + (i*2+p)*12;
        u[0]=S0*inv32; u[1]=S1*inv32; u[2]=Sb*inv32;
        u[3]=Q00*inv32; u[4]=2.0f*Q01*inv32; u[5]=2.0f*Q0b*inv32;
        u[6]=Q11*inv32; u[7]=2.0f*Q1b*inv32; u[8]=Qbb*inv32;
        u[9]=ob[pa]*sc*(1.0f/16.0f); u[10]=ob[pa+1]*sc*(1.0f/16.0f);
        u[11]=0.0f;
    }
}

// ---------------- one FiLM path; z and LN stats read from LDS ----------------
__device__ __forceinline__ void film_path(
    const unsigned short* __restrict__ fb, int slotg, int slotb, int lane,
    int kaf, int path, const float* Z, const float* ST,
    const bf16x8 a2[2], const f4 pv[5], const float* __restrict__ u,
    float (&f0)[2][4], float (&f1)[2][4])
{
    const int g = lane >> 4;
    bf16x8 gh0 = *(const bf16x8*)(fb + slotg * 1024 + lane * 8);
    bf16x8 gh1 = *(const bf16x8*)(fb + slotg * 1024 + 512 + lane * 8);
    bf16x8 bh0 = *(const bf16x8*)(fb + slotb * 1024 + lane * 8);
    bf16x8 bh1 = *(const bf16x8*)(fb + slotb * 1024 + 512 + lane * 8);
    float gbL = pv[2][2], gbH = pv[2][3], bbL = pv[3][0], bbH = pv[3][1];
    f4 cg0 = {gbL, gbL, gbL, gbL}, cg1 = {gbH, gbH, gbH, gbH};
    f4 cb0 = {bbL, bbL, bbL, bbL}, cb1 = {bbH, bbH, bbH, bbH};
    f4 gacc[2][2], bacc[2][2];
    #pragma unroll
    for (int t = 0; t < 2; ++t) {
        gacc[t][0] = __builtin_amdgcn_mfma_f32_16x16x32_bf16(a2[t], gh0, cg0, 0, 0, 0);
        gacc[t][1] = __builtin_amdgcn_mfma_f32_16x16x32_bf16(a2[t], gh1, cg1, 0, 0, 0);
        bacc[t][0] = __builtin_amdgcn_mfma_f32_16x16x32_bf16(a2[t], bh0, cb0, 0, 0, 0);
        bacc[t][1] = __builtin_amdgcn_mfma_f32_16x16x32_bf16(a2[t], bh1, cb1, 0, 0, 0);
    }
    float ob0 = u[9], ob1 = u[10];
    float wk0L=pv[0][0], wk1L=pv[0][1], bL=pv[0][2], lngL=pv[0][3];
    float wk0H=pv[1][0], wk1H=pv[1][1], bH=pv[1][2], lngH=pv[1][3];
    float lnbL=pv[2][0], lnbH=pv[2][1];
    float owL0=pv[3][2], owL1=pv[3][3], owH0=pv[4][0], owH1=pv[4][1];
    #pragma unroll
    for (int t = 0; t < 2; ++t) {
        #pragma unroll
        for (int q = 0; q < 4; ++q) {
            int rowl = 16 * t + 4 * g + q;
            f2 zkv = *(const f2*)(Z + rowl * RSTRIDE + kaf);       // broadcast read
            f2 st  = *(const f2*)(ST + rowl * RSTRIDE + path * 2); // {-m*rstd, rstd}
            float hL = fmaf(zkv[0], wk0L, fmaf(zkv[1], wk1L, bL));
            float hH = fmaf(zkv[0], wk0H, fmaf(zkv[1], wk1H, bH));
            float nL = fmaf(hL, st[1], fmaf(st[0], lngL, lnbL));
            float nH = fmaf(hH, st[1], fmaf(st[0], lngH, lnbH));
            float gL = gacc[t][0][q], gH = gacc[t][1][q];
            float btL = bacc[t][0][q], btH = bacc[t][1][q];
            float thL = fmaxf(fmaf(gL, nL, nL + btL), 0.0f);
            float thH = fmaxf(fmaf(gH, nH, nH + btH), 0.0f);
            float p0 = fmaf(thL, owL0, fmaf(thH, owH0, ob0));
            float p1 = fmaf(thL, owL1, fmaf(thH, owH1, ob1));
            f0[t][q] = reduce16(p0);
            f1[t][q] = reduce16(p1);
        }
    }
}

__global__ __launch_bounds__(256, 1) void realnvp_mfma(
    const float* __restrict__ x, const float* __restrict__ y,
    const float* __restrict__ embW1, const float* __restrict__ embb1,
    const unsigned short* __restrict__ ws16,
    const float* __restrict__ wsP, const float* __restrict__ wsU,
    float* __restrict__ out_z, float* __restrict__ out_ld)
{
    __shared__ __align__(16) unsigned char ldsbuf[4 * WV_STRIDE];
    const int lane = threadIdx.x & 63;
    const int wv = threadIdx.x >> 6;
    const int r = lane & 15, g = lane >> 4;
    const int rs = lane & 31, hw = lane >> 5;
    unsigned char* T = ldsbuf + wv * WV_STRIDE;            // 32 rows x 80B (e2 transpose)
    float* Z  = (float*)(ldsbuf + wv * WV_STRIDE + Z_OFF); // 32 rows x 6 floats (z)
    float* ST = (float*)(ldsbuf + wv * WV_STRIDE + ST_OFF);// 32 x {-mrT,rstdT,-mrS,rstdS,pad,pad}
    float* FB = (float*)(ldsbuf + wv * WV_STRIDE + FB_OFF);// 32 x {tf0,sf0,tf1,sf1,pad,pad}
    const int row0 = (blockIdx.x * 4 + wv) * 32;

    if (lane < 32) {
        f4 xv = *(const f4*)(x + (size_t)(row0 + rs) * 4);
        f2 lo = {xv.x, xv.y}, hi = {xv.z, xv.w};
        *(f2*)(Z + rs * RSTRIDE) = lo;
        *(f2*)(Z + rs * RSTRIDE + 2) = hi;
    }
    f4 y4[2];
    y4[0] = *(const f4*)(y + (size_t)(row0 + r) * 4);
    y4[1] = *(const f4*)(y + (size_t)(row0 + 16 + r) * 4);
    float ld2 = 0.0f;
    WAITLGKM();

    #pragma unroll 1
    for (int i = 0; i < 8; ++i) {
        const int parity = i & 1;
        const int kaf = parity ? 2 : 0;   // kept-dim offset in z row
        const int pa  = parity ? 0 : 2;   // transform-dim base
        const unsigned short* fb = ws16 + i * 6144;
        const float* pP = wsP + i * 640;
        const float* uT = wsU + (i * 2) * 12;
        const float* uS = uT + 12;

        // ---- LN stats: row-per-lane, paths split across half-waves ----
        {
            f2 zk = *(const f2*)(Z + rs * RSTRIDE + kaf);
            const float* ub = wsU + (i * 2 + hw) * 12;
            f4 u0 = *(const f4*)(ub);        // {S0,S1,Sb,Q00}
            f4 u1 = *(const f4*)(ub + 4);    // {Q01,Q0b,Q11,Q1b}
            f4 u2 = *(const f4*)(ub + 8);    // {Qbb,obc0,obc1,0}
            float za = zk[0], zb = zk[1];
            float m   = fmaf(za, u0[0], fmaf(zb, u0[1], u0[2]));
            float ex2 = fmaf(za, fmaf(za, u0[3], fmaf(zb, u1[0], u1[1])),
                             fmaf(zb, fmaf(zb, u1[2], u1[3]), u2[0]));
            float var = fmaxf(fmaf(-m, m, ex2), 0.0f);
            float rstd = __builtin_amdgcn_rsqf(var + LN_EPS);
            f2 stv = {-m * rstd, rstd};
            *(f2*)(ST + rs * RSTRIDE + hw * 2) = stv;
        }

        f4 ptv[5];
        #pragma unroll
        for (int v = 0; v < 5; ++v) ptv[v] = *(const f4*)(pP + v * 64 + r * 4);

        // ---- e1 = relu(y @ W1 + b1) directly in A-fragment layout ----
        const float* W1 = embW1 + i * 128;
        f4 w1a[4], w1b[4];
        #pragma unroll
        for (int c = 0; c < 4; ++c) {
            w1a[c] = *(const f4*)(W1 + c * 32 + g * 8);
            w1b[c] = *(const f4*)(W1 + c * 32 + g * 8 + 4);
        }
        f4 b1a = *(const f4*)(embb1 + i * 32 + g * 8);
        f4 b1b = *(const f4*)(embb1 + i * 32 + g * 8 + 4);
        bf16x8 a1[2];
        #pragma unroll
        for (int t = 0; t < 2; ++t) {
            unsigned aw[4];
            #pragma unroll
            for (int jp = 0; jp < 4; ++jp) {
                const int j0 = 2 * jp, j1 = 2 * jp + 1;
                float aL = (j0 < 4) ? b1a[j0 & 3] : b1b[j0 & 3];
                float aH = (j1 < 4) ? b1a[j1 & 3] : b1b[j1 & 3];
                #pragma unroll
                for (int c = 0; c < 4; ++c) {
                    aL = fmaf(y4[t][c], (j0 < 4) ? w1a[c][j0 & 3] : w1b[c][j0 & 3], aL);
                    aH = fmaf(y4[t][c], (j1 < 4) ? w1a[c][j1 & 3] : w1b[c][j1 & 3], aH);
                }
                aw[jp] = cvt_pk_bf16(fmaxf(aL, 0.0f), fmaxf(aH, 0.0f));
            }
            i4 ai = {(int)aw[0], (int)aw[1], (int)aw[2], (int)aw[3]};
            a1[t] = __builtin_bit_cast(bf16x8, ai);
        }

        // ---- e2 = relu(e1 @ W2 + b2) via MFMA (hi+lo weights, bias in C) ----
        bf16x8 w2h0 = *(const bf16x8*)(fb + lane * 8);
        bf16x8 w2h1 = *(const bf16x8*)(fb + 512 + lane * 8);
        bf16x8 w2l0 = *(const bf16x8*)(fb + 1024 + lane * 8);
        bf16x8 w2l1 = *(const bf16x8*)(fb + 1536 + lane * 8);
        float b2L = ptv[4][2], b2H = ptv[4][3];
        f4 c2L = {b2L, b2L, b2L, b2L}, c2H = {b2H, b2H, b2H, b2H};
        f4 e2a[2][2];
        #pragma unroll
        for (int t = 0; t < 2; ++t) {
            e2a[t][0] = __builtin_amdgcn_mfma_f32_16x16x32_bf16(a1[t], w2h0, c2L, 0, 0, 0);
            e2a[t][0] = __builtin_amdgcn_mfma_f32_16x16x32_bf16(a1[t], w2l0, e2a[t][0], 0, 0, 0);
            e2a[t][1] = __builtin_amdgcn_mfma_f32_16x16x32_bf16(a1[t], w2h1, c2H, 0, 0, 0);
            e2a[t][1] = __builtin_amdgcn_mfma_f32_16x16x32_bf16(a1[t], w2l1, e2a[t][1], 0, 0, 0);
        }

        // ---- D-layout -> A-layout transpose through LDS ----
        #pragma unroll
        for (int t = 0; t < 2; ++t)
            #pragma unroll
            for (int q = 0; q < 4; ++q) {
                int rowl = 16 * t + 4 * g + q;
                float vl = fmaxf(e2a[t][0][q], 0.0f);
                float vh = fmaxf(e2a[t][1][q], 0.0f);
                *(unsigned*)(T + rowl * 80 + r * 4) = cvt_pk_bf16(vl, vh);
            }
        WAITLGKM();   // drains T pack AND the ST stat write above
        bf16x8 a2[2];
        a2[0] = *(const bf16x8*)(T + r * 80 + g * 16);
        a2[1] = *(const bf16x8*)(T + (16 + r) * 80 + g * 16);

        // ---- t and s FiLM paths (z, stats from LDS) ----
        float tf0[2][4], tf1[2][4], sf0[2][4], sf1[2][4];
        film_path(fb, 2, 3, lane, kaf, 0, Z, ST, a2, ptv, uT, tf0, tf1);
        f4 psv[5];
        #pragma unroll
        for (int v = 0; v < 5; ++v) psv[v] = *(const f4*)(pP + 320 + v * 64 + r * 4);
        film_path(fb, 4, 5, lane, kaf, 1, Z, ST, a2, psv, uS, sf0, sf1);

        // ---- publish per-row results (one writer lane per group) ----
        if (r == 0) {
            #pragma unroll
            for (int t = 0; t < 2; ++t)
                #pragma unroll
                for (int q = 0; q < 4; ++q) {
                    int rowl = 16 * t + 4 * g + q;
                    f2 lo = {tf0[t][q], sf0[t][q]};
                    f2 hi = {tf1[t][q], sf1[t][q]};
                    *(f2*)(FB + rowl * RSTRIDE) = lo;
                    *(f2*)(FB + rowl * RSTRIDE + 2) = hi;
                }
        }
        WAITLGKM();

        // ---- coupling tail: row-per-lane, dims split across half-waves ----
        {
            int d = pa + hw;
            f2 fv = *(const f2*)(FB + rs * RSTRIDE + hw * 2);   // {tf_d, sf_d}
            float e  = __builtin_amdgcn_exp2f(fv[1]);     // sf pre-scaled by 2*log2e
            float rc = __builtin_amdgcn_rcpf(e + 1.0f);
            float s2 = fmaf(-2.0f * LOG2E, rc, LOG2E);    // tanh(.)*log2e
            float eA = __builtin_amdgcn_exp2f(s2);
            float zo = Z[rs * RSTRIDE + d];
            Z[rs * RSTRIDE + d] = fmaf(zo, eA, fv[0]);
            ld2 += s2;
        }
        WAITLGKM();
    }

    float oth = __shfl(ld2, lane ^ 32, 64);
    float ldv = (ld2 + oth) * LN2;
    if (lane < 32) {
        f2 lo = *(const f2*)(Z + rs * RSTRIDE);
        f2 hi = *(const f2*)(Z + rs * RSTRIDE + 2);
        f4 zo = {lo[0], lo[1], hi[0], hi[1]};
        *(f4*)(out_z + (size_t)(row0 + rs) * 4) = zo;
        out_ld[row0 + rs] = ldv;
    }
}

extern "C" void kernel_launch(void* const* d_in, const int* in_sizes, int n_in,
                              void* d_out, int out_size, void* d_ws, size_t ws_size,
                              hipStream_t stream) {
    const float* x      = (const float*)d_in[0];
    const float* y      = (const float*)d_in[1];
    const float* embW1  = (const float*)d_in[2];
    const float* embb1  = (const float*)d_in[3];
    const float* embW2  = (const float*)d_in[4];
    const float* embb2  = (const float*)d_in[5];
    const float* tW     = (const float*)d_in[6];
    const float* tb     = (const float*)d_in[7];
    const float* t_ln_g = (const float*)d_in[8];
    const float* t_ln_b = (const float*)d_in[9];
    const float* t_gW   = (const float*)d_in[10];
    const float* t_gb   = (const float*)d_in[11];
    const float* t_bW   = (const float*)d_in[12];
    const float* t_bb   = (const float*)d_in[13];
    const float* toW    = (const float*)d_in[14];
    const float* tob    = (const float*)d_in[15];
    const float* sW     = (const float*)d_in[16];
    const float* sb     = (const float*)d_in[17];
    const float* s_ln_g = (const float*)d_in[18];
    const float* s_ln_b = (const float*)d_in[19];
    const float* s_gW   = (const float*)d_in[20];
    const float* s_gb   = (const float*)d_in[21];
    const float* s_bW   = (const float*)d_in[22];
    const float* s_bb   = (const float*)d_in[23];
    const float* soW    = (const float*)d_in[24];
    const float* sob    = (const float*)d_in[25];

    if (ws_size < WS_NEED) return;
    unsigned short* ws16 = (unsigned short*)d_ws;
    float* wsP = (float*)((char*)d_ws + WS_PARM_OFF);
    float* wsU = (float*)((char*)d_ws + WS_UNIF_OFF);

    int B = in_sizes[0] / 4;
    float* out_z  = (float*)d_out;
    float* out_ld = out_z + (size_t)B * 4;

    hipLaunchKernelGGL(preproc_kernel, dim3(8), dim3(256), 0, stream,
                       embW2, embb2, tW, tb, t_ln_g, t_ln_b, t_gW, t_gb,
                       t_bW, t_bb, toW, tob, sW, sb, s_ln_g, s_ln_b,
                       s_gW, s_gb, s_bW, s_bb, soW, sob, ws16, wsP, wsU);
    hipLaunchKernelGGL(realnvp_mfma, dim3(B / 128), dim3(256), 0, stream,
                       x, y, embW1, embb1, ws16, wsP, wsU, out_z, out_ld);
}

// Round 13
// 108.157 us; speedup vs baseline: 3.1503x; 1.1239x over previous
//
#include <hip/hip_runtime.h>
#include <math.h>

#define LN_EPS 1e-5f
#define LOG2E 1.44269504088896f
#define LN2   0.69314718055994531f

typedef float f4 __attribute__((ext_vector_type(4)));
typedef float f2 __attribute__((ext_vector_type(2)));
typedef int   i4 __attribute__((ext_vector_type(4)));
typedef short bf16x8 __attribute__((ext_vector_type(8)));

// d_ws layout (bytes):
//   [0, 98304)        frags: [layer8][slot6][half2][lane64][j8] bf16
//                     slots: 0=W2hi 1=W2lo 2=tG 3=tB 4=sG 5=sB
//   [98304, 139264)   params: [layer8][path2][vec5][r16][4] f32
//   [139264, 140032)  uniforms: [layer8][path2][12] f32
#define WS_PARM_OFF 98304
#define WS_UNIF_OFF 139264
#define WS_NEED 140032

// per-wave LDS: T(2560) | Z(768) | STC(1024) | FB(768) = 5120 B
#define WV_STRIDE 5120
#define Z_OFF   2560
#define STC_OFF 3328
#define FB_OFF  4352
// Z/FB row stride: 6 floats (24B). STC row stride: 8 floats (32B) so both
// 16B path-slots are b128-aligned; STC reads are broadcast (conflict-free).
#define RSTRIDE 6

// Compiler-only fence: prevents reordering of TBAA-distinct LDS accesses
// (unsigned stores vs short8 loads; cross-lane float traffic). LDS ops from
// one wave execute in program order in hardware, and the compiler inserts
// lgkmcnt waits before register consumption of its own loads — so no
// runtime drain is needed for same-wave cross-lane W->R.
#define CBAR() asm volatile("" ::: "memory")

__device__ __forceinline__ unsigned short rne_bf16(float f) {
    unsigned u = __builtin_bit_cast(unsigned, f);
    unsigned r = (u + 0x7FFFu + ((u >> 16) & 1u)) >> 16;
    return (unsigned short)r;
}

// packed f32->bf16 convert (RNE), one VALU op for two conversions
__device__ __forceinline__ unsigned cvt_pk_bf16(float lo, float hi) {
    unsigned r;
    asm("v_cvt_pk_bf16_f32 %0, %1, %2" : "=v"(r) : "v"(lo), "v"(hi));
    return r;
}

template <int CTRL>
__device__ __forceinline__ float dpp_add_step(float v) {
    int t = __builtin_amdgcn_update_dpp(0, __builtin_bit_cast(int, v), CTRL, 0xf, 0xf, true);
    return v + __builtin_bit_cast(float, t);
}
// sum across the 16-lane DPP row; result identical in all 16 lanes
__device__ __forceinline__ float reduce16(float v) {
    v = dpp_add_step<0xB1>(v);   // quad_perm(1,0,3,2)
    v = dpp_add_step<0x4E>(v);   // quad_perm(2,3,0,1)
    v = dpp_add_step<0x141>(v);  // row_half_mirror
    v = dpp_add_step<0x140>(v);  // row_mirror
    return v;
}

// ---------------- preprocessing (identical to round 10-12) ----------------
__global__ void preproc_kernel(
    const float* __restrict__ embW2, const float* __restrict__ embb2,
    const float* __restrict__ tW, const float* __restrict__ tb,
    const float* __restrict__ t_ln_g, const float* __restrict__ t_ln_b,
    const float* __restrict__ t_gW, const float* __restrict__ t_gb,
    const float* __restrict__ t_bW, const float* __restrict__ t_bb,
    const float* __restrict__ toW, const float* __restrict__ tob,
    const float* __restrict__ sW, const float* __restrict__ sb,
    const float* __restrict__ s_ln_g, const float* __restrict__ s_ln_b,
    const float* __restrict__ s_gW, const float* __restrict__ s_gb,
    const float* __restrict__ s_bW, const float* __restrict__ s_bb,
    const float* __restrict__ soW, const float* __restrict__ sob,
    unsigned short* __restrict__ ws16, float* __restrict__ wsP,
    float* __restrict__ wsU)
{
    const int i = blockIdx.x;
    const int tid = threadIdx.x;
    const int parity = i & 1;
    const int ka = parity ? 2 : 0, pa = parity ? 0 : 2;

    const float* fsrc[6] = {embW2 + i * 1024, embW2 + i * 1024,
                            t_gW + i * 1024, t_bW + i * 1024,
                            s_gW + i * 1024, s_bW + i * 1024};
    for (int e = tid; e < 6144; e += 256) {
        int s = e >> 10, e10 = e & 1023;
        int half = e10 >> 9, ln = (e10 >> 3) & 63, j = e10 & 7;
        int p8 = (ln >> 4) * 8 + j;
        int k = (s >= 2) ? ((p8 >> 1) | ((p8 & 1) << 4)) : p8;
        int c = half * 16 + (ln & 15);
        float w = fsrc[s][k * 32 + c];
        unsigned short hv = rne_bf16(w);
        if (s == 1) {
            float whi = __builtin_bit_cast(float, (unsigned)hv << 16);
            hv = rne_bf16(w - whi);
        }
        ws16[i * 6144 + s * 1024 + e10] = hv;
    }

    if (tid < 32) {
        int p = tid >> 4, r = tid & 15;
        const float* W   = (p ? sW : tW) + i * 128;
        const float* b   = (p ? sb : tb) + i * 32;
        const float* lng = (p ? s_ln_g : t_ln_g) + i * 32;
        const float* lnb = (p ? s_ln_b : t_ln_b) + i * 32;
        const float* gb  = (p ? s_gb : t_gb) + i * 32;
        const float* bb  = (p ? s_bb : t_bb) + i * 32;
        const float* ow  = (p ? soW : toW) + i * 128;
        float sc = p ? (2.0f * LOG2E) : 1.0f;
        int cL = r, cH = r + 16;
        float* dst = wsP + i * 640 + p * 320;
        f4 v0 = {W[ka*32+cL]*lng[cL], W[(ka+1)*32+cL]*lng[cL], b[cL]*lng[cL], lng[cL]};
        f4 v1 = {W[ka*32+cH]*lng[cH], W[(ka+1)*32+cH]*lng[cH], b[cH]*lng[cH], lng[cH]};
        f4 v2 = {lnb[cL], lnb[cH], gb[cL], gb[cH]};
        f4 v3 = {bb[cL], bb[cH], ow[cL*4+pa]*sc, ow[cL*4+pa+1]*sc};
        f4 v4 = {ow[cH*4+pa]*sc, ow[cH*4+pa+1]*sc, embb2[i*32+cL], embb2[i*32+cH]};
        *(f4*)(dst + 0*64 + r*4) = v0;
        *(f4*)(dst + 1*64 + r*4) = v1;
        *(f4*)(dst + 2*64 + r*4) = v2;
        *(f4*)(dst + 3*64 + r*4) = v3;
        *(f4*)(dst + 4*64 + r*4) = v4;
    } else if (tid < 34) {
        int p = tid - 32;
        const float* W  = (p ? sW : tW) + i * 128;
        const float* b  = (p ? sb : tb) + i * 32;
        const float* ob = (p ? sob : tob) + i * 4;
        float sc = p ? (2.0f * LOG2E) : 1.0f;
        float S0=0,S1=0,Sb=0,Q00=0,Q11=0,Qbb=0,Q01=0,Q0b=0,Q1b=0;
        for (int c = 0; c < 32; ++c) {
            float w0 = W[ka*32+c], w1 = W[(ka+1)*32+c], bc = b[c];
            S0+=w0; S1+=w1; Sb+=bc;
            Q00+=w0*w0; Q11+=w1*w1; Qbb+=bc*bc;
            Q01+=w0*w1; Q0b+=w0*bc; Q1b+=w1*bc;
        }
        const float inv32 = 1.0f / 32.0f;
        float* u = wsU + (i*2+p)*12;
        u[0]=S0*inv32; u[1]=S1*inv32; u[2]=Sb*inv32;
        u[3]=Q00*inv32; u[4]=2.0f*Q01*inv32; u[5]=2.0f*Q0b*inv32;
        u[6]=Q11*inv32; u[7]=2.0f*Q1b*inv32; u[8]=Qbb*inv32;
        u[9]=ob[pa]*sc*(1.0f/16.0f); u[10]=ob[pa+1]*sc*(1.0f/16.0f);
        u[11]=0.0f;
    }
}

// ---------------- one FiLM path; zk + LN stats from one packed LDS record ----------------
__device__ __forceinline__ void film_path(
    const unsigned short* __restrict__ fb, int slotg, int slotb, int lane,
    int path, const float* STC,
    const bf16x8 a2[2], const f4 pv[5], const float* __restrict__ u,
    float (&f0)[2][4], float (&f1)[2][4])
{
    const int g = lane >> 4;
    bf16x8 gh0 = *(const bf16x8*)(fb + slotg * 1024 + lane * 8);
    bf16x8 gh1 = *(const bf16x8*)(fb + slotg * 1024 + 512 + lane * 8);
    bf16x8 bh0 = *(const bf16x8*)(fb + slotb * 1024 + lane * 8);
    bf16x8 bh1 = *(const bf16x8*)(fb + slotb * 1024 + 512 + lane * 8);
    float gbL = pv[2][2], gbH = pv[2][3], bbL = pv[3][0], bbH = pv[3][1];
    f4 cg0 = {gbL, gbL, gbL, gbL}, cg1 = {gbH, gbH, gbH, gbH};
    f4 cb0 = {bbL, bbL, bbL, bbL}, cb1 = {bbH, bbH, bbH, bbH};
    f4 gacc[2][2], bacc[2][2];
    #pragma unroll
    for (int t = 0; t < 2; ++t) {
        gacc[t][0] = __builtin_amdgcn_mfma_f32_16x16x32_bf16(a2[t], gh0, cg0, 0, 0, 0);
        gacc[t][1] = __builtin_amdgcn_mfma_f32_16x16x32_bf16(a2[t], gh1, cg1, 0, 0, 0);
        bacc[t][0] = __builtin_amdgcn_mfma_f32_16x16x32_bf16(a2[t], bh0, cb0, 0, 0, 0);
        bacc[t][1] = __builtin_amdgcn_mfma_f32_16x16x32_bf16(a2[t], bh1, cb1, 0, 0, 0);
    }
    float ob0 = u[9], ob1 = u[10];
    float wk0L=pv[0][0], wk1L=pv[0][1], bL=pv[0][2], lngL=pv[0][3];
    float wk0H=pv[1][0], wk1H=pv[1][1], bH=pv[1][2], lngH=pv[1][3];
    float lnbL=pv[2][0], lnbH=pv[2][1];
    float owL0=pv[3][2], owL1=pv[3][3], owH0=pv[4][0], owH1=pv[4][1];
    #pragma unroll
    for (int t = 0; t < 2; ++t) {
        #pragma unroll
        for (int q = 0; q < 4; ++q) {
            int rowl = 16 * t + 4 * g + q;
            // one b128 broadcast read: {zka, zkb, -m*rstd, rstd}
            f4 stc = *(const f4*)(STC + rowl * 8 + path * 4);
            float hL = fmaf(stc[0], wk0L, fmaf(stc[1], wk1L, bL));
            float hH = fmaf(stc[0], wk0H, fmaf(stc[1], wk1H, bH));
            float nL = fmaf(hL, stc[3], fmaf(stc[2], lngL, lnbL));
            float nH = fmaf(hH, stc[3], fmaf(stc[2], lngH, lnbH));
            float gL = gacc[t][0][q], gH = gacc[t][1][q];
            float btL = bacc[t][0][q], btH = bacc[t][1][q];
            float thL = fmaxf(fmaf(gL, nL, nL + btL), 0.0f);
            float thH = fmaxf(fmaf(gH, nH, nH + btH), 0.0f);
            float p0 = fmaf(thL, owL0, fmaf(thH, owH0, ob0));
            float p1 = fmaf(thL, owL1, fmaf(thH, owH1, ob1));
            f0[t][q] = reduce16(p0);
            f1[t][q] = reduce16(p1);
        }
    }
}

__global__ __launch_bounds__(256, 1) void realnvp_mfma(
    const float* __restrict__ x, const float* __restrict__ y,
    const float* __restrict__ embW1, const float* __restrict__ embb1,
    const unsigned short* __restrict__ ws16,
    const float* __restrict__ wsP, const float* __restrict__ wsU,
    float* __restrict__ out_z, float* __restrict__ out_ld)
{
    __shared__ __align__(16) unsigned char ldsbuf[4 * WV_STRIDE];
    const int lane = threadIdx.x & 63;
    const int wv = threadIdx.x >> 6;
    const int r = lane & 15, g = lane >> 4;
    const int rs = lane & 31, hw = lane >> 5;
    unsigned char* T  = ldsbuf + wv * WV_STRIDE;             // 32 rows x 80B (e2 transpose)
    float* Z   = (float*)(ldsbuf + wv * WV_STRIDE + Z_OFF);  // 32 rows x 6 floats (z)
    float* STC = (float*)(ldsbuf + wv * WV_STRIDE + STC_OFF);// 32 x 2 x {zka,zkb,-mr,rstd}
    float* FB  = (float*)(ldsbuf + wv * WV_STRIDE + FB_OFF); // 32 x {tf0,sf0,tf1,sf1,pad,pad}
    const int row0 = (blockIdx.x * 4 + wv) * 32;

    if (lane < 32) {
        f4 xv = *(const f4*)(x + (size_t)(row0 + rs) * 4);
        f2 lo = {xv.x, xv.y}, hi = {xv.z, xv.w};
        *(f2*)(Z + rs * RSTRIDE) = lo;
        *(f2*)(Z + rs * RSTRIDE + 2) = hi;
    }
    f4 y4[2];
    y4[0] = *(const f4*)(y + (size_t)(row0 + r) * 4);
    y4[1] = *(const f4*)(y + (size_t)(row0 + 16 + r) * 4);
    float ld2 = 0.0f;
    CBAR();

    #pragma unroll 1
    for (int i = 0; i < 8; ++i) {
        const int parity = i & 1;
        const int kaf = parity ? 2 : 0;   // kept-dim offset in z row
        const int pa  = parity ? 0 : 2;   // transform-dim base
        const unsigned short* fb = ws16 + i * 6144;
        const float* pP = wsP + i * 640;
        const float* uT = wsU + (i * 2) * 12;
        const float* uS = uT + 12;

        // ---- LN stats: row-per-lane, paths split across half-waves.
        //      Writes one packed b128 record {zka, zkb, -m*rstd, rstd}. ----
        {
            f2 zk = *(const f2*)(Z + rs * RSTRIDE + kaf);
            const float* ub = wsU + (i * 2 + hw) * 12;
            f4 u0 = *(const f4*)(ub);        // {S0,S1,Sb,Q00}
            f4 u1 = *(const f4*)(ub + 4);    // {Q01,Q0b,Q11,Q1b}
            f4 u2 = *(const f4*)(ub + 8);    // {Qbb,obc0,obc1,0}
            float za = zk[0], zb = zk[1];
            float m   = fmaf(za, u0[0], fmaf(zb, u0[1], u0[2]));
            float ex2 = fmaf(za, fmaf(za, u0[3], fmaf(zb, u1[0], u1[1])),
                             fmaf(zb, fmaf(zb, u1[2], u1[3]), u2[0]));
            float var = fmaxf(fmaf(-m, m, ex2), 0.0f);
            float rstd = __builtin_amdgcn_rsqf(var + LN_EPS);
            f4 rec = {za, zb, -m * rstd, rstd};
            *(f4*)(STC + rs * 8 + hw * 4) = rec;
        }
        CBAR();

        f4 ptv[5];
        #pragma unroll
        for (int v = 0; v < 5; ++v) ptv[v] = *(const f4*)(pP + v * 64 + r * 4);

        // ---- e1 = relu(y @ W1 + b1) directly in A-fragment layout ----
        const float* W1 = embW1 + i * 128;
        f4 w1a[4], w1b[4];
        #pragma unroll
        for (int c = 0; c < 4; ++c) {
            w1a[c] = *(const f4*)(W1 + c * 32 + g * 8);
            w1b[c] = *(const f4*)(W1 + c * 32 + g * 8 + 4);
        }
        f4 b1a = *(const f4*)(embb1 + i * 32 + g * 8);
        f4 b1b = *(const f4*)(embb1 + i * 32 + g * 8 + 4);
        bf16x8 a1[2];
        #pragma unroll
        for (int t = 0; t < 2; ++t) {
            unsigned aw[4];
            #pragma unroll
            for (int jp = 0; jp < 4; ++jp) {
                const int j0 = 2 * jp, j1 = 2 * jp + 1;
                float aL = (j0 < 4) ? b1a[j0 & 3] : b1b[j0 & 3];
                float aH = (j1 < 4) ? b1a[j1 & 3] : b1b[j1 & 3];
                #pragma unroll
                for (int c = 0; c < 4; ++c) {
                    aL = fmaf(y4[t][c], (j0 < 4) ? w1a[c][j0 & 3] : w1b[c][j0 & 3], aL);
                    aH = fmaf(y4[t][c], (j1 < 4) ? w1a[c][j1 & 3] : w1b[c][j1 & 3], aH);
                }
                aw[jp] = cvt_pk_bf16(fmaxf(aL, 0.0f), fmaxf(aH, 0.0f));
            }
            i4 ai = {(int)aw[0], (int)aw[1], (int)aw[2], (int)aw[3]};
            a1[t] = __builtin_bit_cast(bf16x8, ai);
        }

        // ---- e2 = relu(e1 @ W2 + b2) via MFMA (hi+lo weights, bias in C) ----
        bf16x8 w2h0 = *(const bf16x8*)(fb + lane * 8);
        bf16x8 w2h1 = *(const bf16x8*)(fb + 512 + lane * 8);
        bf16x8 w2l0 = *(const bf16x8*)(fb + 1024 + lane * 8);
        bf16x8 w2l1 = *(const bf16x8*)(fb + 1536 + lane * 8);
        float b2L = ptv[4][2], b2H = ptv[4][3];
        f4 c2L = {b2L, b2L, b2L, b2L}, c2H = {b2H, b2H, b2H, b2H};
        f4 e2a[2][2];
        #pragma unroll
        for (int t = 0; t < 2; ++t) {
            e2a[t][0] = __builtin_amdgcn_mfma_f32_16x16x32_bf16(a1[t], w2h0, c2L, 0, 0, 0);
            e2a[t][0] = __builtin_amdgcn_mfma_f32_16x16x32_bf16(a1[t], w2l0, e2a[t][0], 0, 0, 0);
            e2a[t][1] = __builtin_amdgcn_mfma_f32_16x16x32_bf16(a1[t], w2h1, c2H, 0, 0, 0);
            e2a[t][1] = __builtin_amdgcn_mfma_f32_16x16x32_bf16(a1[t], w2l1, e2a[t][1], 0, 0, 0);
        }

        // ---- D-layout -> A-layout transpose through LDS ----
        CBAR();   // order unsigned T-stores vs earlier short T-loads (TBAA)
        #pragma unroll
        for (int t = 0; t < 2; ++t)
            #pragma unroll
            for (int q = 0; q < 4; ++q) {
                int rowl = 16 * t + 4 * g + q;
                float vl = fmaxf(e2a[t][0][q], 0.0f);
                float vh = fmaxf(e2a[t][1][q], 0.0f);
                *(unsigned*)(T + rowl * 80 + r * 4) = cvt_pk_bf16(vl, vh);
            }
        CBAR();   // order T-stores before a2 loads (in-order LDS does the rest)
        bf16x8 a2[2];
        a2[0] = *(const bf16x8*)(T + r * 80 + g * 16);
        a2[1] = *(const bf16x8*)(T + (16 + r) * 80 + g * 16);

        // ---- t and s FiLM paths (zk+stats from packed STC records) ----
        float tf0[2][4], tf1[2][4], sf0[2][4], sf1[2][4];
        film_path(fb, 2, 3, lane, 0, STC, a2, ptv, uT, tf0, tf1);
        f4 psv[5];
        #pragma unroll
        for (int v = 0; v < 5; ++v) psv[v] = *(const f4*)(pP + 320 + v * 64 + r * 4);
        film_path(fb, 4, 5, lane, 1, STC, a2, psv, uS, sf0, sf1);

        // ---- publish per-row results (one writer lane per group) ----
        if (r == 0) {
            #pragma unroll
            for (int t = 0; t < 2; ++t)
                #pragma unroll
                for (int q = 0; q < 4; ++q) {
                    int rowl = 16 * t + 4 * g + q;
                    f2 lo = {tf0[t][q], sf0[t][q]};
                    f2 hi = {tf1[t][q], sf1[t][q]};
                    *(f2*)(FB + rowl * RSTRIDE) = lo;
                    *(f2*)(FB + rowl * RSTRIDE + 2) = hi;
                }
        }
        CBAR();

        // ---- coupling tail: row-per-lane, dims split across half-waves ----
        {
            int d = pa + hw;
            f2 fv = *(const f2*)(FB + rs * RSTRIDE + hw * 2);   // {tf_d, sf_d}
            float e  = __builtin_amdgcn_exp2f(fv[1]);     // sf pre-scaled by 2*log2e
            float rc = __builtin_amdgcn_rcpf(e + 1.0f);
            float s2 = fmaf(-2.0f * LOG2E, rc, LOG2E);    // tanh(.)*log2e
            float eA = __builtin_amdgcn_exp2f(s2);
            float zo = Z[rs * RSTRIDE + d];
            Z[rs * RSTRIDE + d] = fmaf(zo, eA, fv[0]);
            ld2 += s2;
        }
        CBAR();
    }

    float oth = __shfl(ld2, lane ^ 32, 64);
    float ldv = (ld2 + oth) * LN2;
    if (lane < 32) {
        f2 lo = *(const f2*)(Z + rs * RSTRIDE);
        f2 hi = *(const f2*)(Z + rs * RSTRIDE + 2);
        f4 zo = {lo[0], lo[1], hi[0], hi[1]};
        *(f4*)(out_z + (size_t)(row0 + rs) * 4) = zo;
        out_ld[row0 + rs] = ldv;
    }
}

extern "C" void kernel_launch(void* const* d_in, const int* in_sizes, int n_in,
                              void* d_out, int out_size, void* d_ws, size_t ws_size,
                              hipStream_t stream) {
    const float* x      = (const float*)d_in[0];
    const float* y      = (const float*)d_in[1];
    const float* embW1  = (const float*)d_in[2];
    const float* embb1  = (const float*)d_in[3];
    const float* embW2  = (const float*)d_in[4];
    const float* embb2  = (const float*)d_in[5];
    const float* tW     = (const float*)d_in[6];
    const float* tb     = (const float*)d_in[7];
    const float* t_ln_g = (const float*)d_in[8];
    const float* t_ln_b = (const float*)d_in[9];
    const float* t_gW   = (const float*)d_in[10];
    const float* t_gb   = (const float*)d_in[11];
    const float* t_bW   = (const float*)d_in[12];
    const float* t_bb   = (const float*)d_in[13];
    const float* toW    = (const float*)d_in[14];
    const float* tob    = (const float*)d_in[15];
    const float* sW     = (const float*)d_in[16];
    const float* sb     = (const float*)d_in[17];
    const float* s_ln_g = (const float*)d_in[18];
    const float* s_ln_b = (const float*)d_in[19];
    const float* s_gW   = (const float*)d_in[20];
    const float* s_gb   = (const float*)d_in[21];
    const float* s_bW   = (const float*)d_in[22];
    const float* s_bb   = (const float*)d_in[23];
    const float* soW    = (const float*)d_in[24];
    const float* sob    = (const float*)d_in[25];

    if (ws_size < WS_NEED) return;
    unsigned short* ws16 = (unsigned short*)d_ws;
    float* wsP = (float*)((char*)d_ws + WS_PARM_OFF);
    float* wsU = (float*)((char*)d_ws + WS_UNIF_OFF);

    int B = in_sizes[0] / 4;
    float* out_z  = (float*)d_out;
    float* out_ld = out_z + (size_t)B * 4;

    hipLaunchKernelGGL(preproc_kernel, dim3(8), dim3(256), 0, stream,
                       embW2, embb2, tW, tb, t_ln_g, t_ln_b, t_gW, t_gb,
                       t_bW, t_bb, toW, tob, sW, sb, s_ln_g, s_ln_b,
                       s_gW, s_gb, s_bW, s_bb, soW, sob, ws16, wsP, wsU);
    hipLaunchKernelGGL(realnvp_mfma, dim3(B / 128), dim3(256), 0, stream,
                       x, y, embW1, embb1, ws16, wsP, wsU, out_z, out_ld);
}